// Round 5
// baseline (277.975 us; speedup 1.0000x reference)
//
#include <hip/hip_runtime.h>
#include <hip/hip_bf16.h>

// ---------------------------------------------------------------------------
// TransformerBlock: x[2,2048,1024] fp32 -> out fp32
// bf16 MFMA GEMMs (dbuf global_load_lds staging, XCD-chunked swizzle)
// + swapped-QK^T flash attention.
// ---------------------------------------------------------------------------

using f32x4 = __attribute__((ext_vector_type(4))) float;
using s16x8 = __attribute__((ext_vector_type(8))) short;

constexpr int D_MODEL = 1024;
constexpr int D_FF    = 4096;
constexpr int DK      = 64;
constexpr int BB      = 2;
constexpr int SS      = 2048;
constexpr int NTOK    = BB * SS;   // 4096

// 0.125 (1/sqrt(dk)) * log2(e): folded into Q at the QK-projection epilogue,
// so attention softmax can use exp2 directly.
#define QSCALE 0.18033688011112042f

__device__ __forceinline__ ushort f2bf(float f) {
    unsigned u = __float_as_uint(f);
    u += 0x7fffu + ((u >> 16) & 1u);   // round-to-nearest-even
    return (ushort)(u >> 16);
}

__device__ __forceinline__ float ex2(float x) {
    float r;
    asm("v_exp_f32 %0, %1" : "=v"(r) : "v"(x));
    return r;
}

__device__ __forceinline__ void gload_lds16(const void* g, void* l) {
    __builtin_amdgcn_global_load_lds(
        (const __attribute__((address_space(1))) void*)g,
        (__attribute__((address_space(3))) void*)l, 16, 0, 0);
}

// ---------------------------- fp32 -> bf16 convert -------------------------
__global__ void cvt_kernel(const float* __restrict__ in, ushort* __restrict__ out, int n) {
    int i = (blockIdx.x * blockDim.x + threadIdx.x) * 4;
    if (i + 3 < n) {
        float4 v = *(const float4*)(in + i);
        ushort4 o;
        o.x = f2bf(v.x); o.y = f2bf(v.y); o.z = f2bf(v.z); o.w = f2bf(v.w);
        *(ushort4*)(out + i) = o;
    }
}

// ---------------------------- GEMM: C = A * W^T + bias ---------------------
// A: [M,K] bf16. W: [N,K] bf16. C: [M,N] fp32 or bf16.
// 128x128 tile, BK=64, 4 waves (2x2), each wave 64x64 via 4x4 16x16x32 frags.
// Double-buffered LDS, ONE barrier per K-step: stage(next) overlaps
// compute(cur); the barrier's implicit vmcnt(0) drains ~350 cy after issue.
// 1-D grid, XCD-chunked swizzle: HW XCD = id%8 gets contiguous tile chunk.
template <bool RELU, bool OUTBF16, bool BIASROW, bool SCALEQ>
__global__ __launch_bounds__(256, 2) void gemm_bt(
        const ushort* __restrict__ A, const ushort* __restrict__ W,
        const float* __restrict__ bias, const float* __restrict__ bias2, int nsplit,
        void* __restrict__ Cout, int M, int N, int K, int gx) {
    __shared__ __align__(16) char Asb[2][128 * 128];
    __shared__ __align__(16) char Bsb[2][128 * 128];

    const int nwg = (int)gridDim.x;
    const int id  = (int)blockIdx.x;
    const int sw  = (id & 7) * (nwg >> 3) + (id >> 3);
    const int bx  = sw % gx, by = sw / gx;

    const int t  = threadIdx.x;
    const int l  = t & 63;
    const int w  = t >> 6;
    const int wr = w >> 1, wc = w & 1;
    const int li = l & 15, g = l >> 4;
    const int bm0 = by << 7;
    const int bn0 = bx << 7;

    f32x4 acc[4][4];
#pragma unroll
    for (int m = 0; m < 4; ++m)
#pragma unroll
        for (int n = 0; n < 4; ++n)
            acc[m][n] = (f32x4){0.f, 0.f, 0.f, 0.f};

    const int rsub = l >> 3, slot = l & 7;
    const int swzel = (((slot * 16) ^ (rsub << 4)) >> 1);   // element offset in 64-chunk

    auto stage = [&](int buf, int k0) {
#pragma unroll
        for (int i = 0; i < 4; ++i) {
            const int rbase = i * 32 + w * 8;   // wave-uniform LDS dest base
            gload_lds16(A + (size_t)(bm0 + rbase + rsub) * K + k0 + swzel,
                        Asb[buf] + rbase * 128);
            gload_lds16(W + (size_t)(bn0 + rbase + rsub) * K + k0 + swzel,
                        Bsb[buf] + rbase * 128);
        }
    };

    const int nk = K >> 6;
    stage(0, 0);
    __syncthreads();

    for (int tt = 0; tt < nk; ++tt) {
        const int cur = tt & 1;
        if (tt + 1 < nk) stage(cur ^ 1, (tt + 1) << 6);
#pragma unroll
        for (int ks = 0; ks < 2; ++ks) {
            s16x8 af[4], bfr[4];
#pragma unroll
            for (int m = 0; m < 4; ++m) {
                int row = wr * 64 + m * 16 + li;
                af[m] = *(const s16x8*)(Asb[cur] + row * 128 + (((ks * 4 + g) * 16) ^ ((row & 7) << 4)));
            }
#pragma unroll
            for (int n = 0; n < 4; ++n) {
                int row = wc * 64 + n * 16 + li;
                bfr[n] = *(const s16x8*)(Bsb[cur] + row * 128 + (((ks * 4 + g) * 16) ^ ((row & 7) << 4)));
            }
            __builtin_amdgcn_s_setprio(1);
#pragma unroll
            for (int m = 0; m < 4; ++m)
#pragma unroll
                for (int n = 0; n < 4; ++n)
                    acc[m][n] = __builtin_amdgcn_mfma_f32_16x16x32_bf16(af[m], bfr[n], acc[m][n], 0, 0, 0);
            __builtin_amdgcn_s_setprio(0);
        }
        __syncthreads();   // drains stage's vmcnt + protects buffer reuse
    }

#pragma unroll
    for (int m = 0; m < 4; ++m) {
        int row0 = bm0 + wr * 64 + m * 16 + g * 4;
#pragma unroll
        for (int n = 0; n < 4; ++n) {
            int col = bn0 + wc * 64 + n * 16 + li;
            float bsv = 0.f;
            if (!BIASROW) bsv = (col < nsplit) ? bias[col] : bias2[col - nsplit];
#pragma unroll
            for (int r = 0; r < 4; ++r) {
                float v = acc[m][n][r] + (BIASROW ? bias[row0 + r] : bsv);
                if (RELU) v = fmaxf(v, 0.f);
                if (SCALEQ && col < nsplit) v *= QSCALE;   // pre-scale Q for exp2 softmax
                size_t idx = (size_t)(row0 + r) * N + col;
                if (OUTBF16) ((ushort*)Cout)[idx] = f2bf(v);
                else         ((float*)Cout)[idx]  = v;
            }
        }
    }
}

// ---------------------------- causal flash attention -----------------------
// QKb: [NTOK][2048] bf16 (Q pre-scaled by QSCALE at col h*64, K at 1024+h*64).
// VtG: [1024][NTOK] bf16 == V^T.
// Block = 4 waves = 64 Q rows of one (b,h); wave w owns rows qb+w*16..+16.
// Swapped QK^T: sa = mfma(K,Q) -> lane holds P[q=li][k=ks*16+g*4+r]:
// row-softmax is lane-local + 2 shfls; P packs to 4 ds_write_b64.
__global__ __launch_bounds__(256, 4) void attn_kernel(
        const ushort* __restrict__ QKb, const ushort* __restrict__ VtG,
        ushort* __restrict__ ctx) {
    __shared__ __align__(16) char Ks[2][64 * 128];
    __shared__ __align__(16) char Vs[2][64 * 128];
    __shared__ __align__(16) char Ps[4][16 * 128];

    const int t  = threadIdx.x;
    const int l  = t & 63;
    const int w  = t >> 6;
    const int li = l & 15, g = l >> 4;
    const int qb = ((int)gridDim.x - 1 - (int)blockIdx.x) * 64;  // big blocks first
    const int h  = blockIdx.y;
    const int b  = blockIdx.z;
    const int qw = qb + w * 16;

    const ushort* Qp = QKb + (size_t)(b * SS + qw) * 2048 + h * DK;
    const ushort* Kp = QKb + (size_t)(b * SS) * 2048 + 1024 + h * DK;
    const ushort* Vp = VtG + (size_t)(h * DK) * NTOK + b * SS;

    s16x8 qf[2];
#pragma unroll
    for (int ds = 0; ds < 2; ++ds)
        qf[ds] = *(const s16x8*)(Qp + li * 2048 + ds * 32 + g * 8);

    f32x4 o[4];
#pragma unroll
    for (int d = 0; d < 4; ++d) o[d] = (f32x4){0.f, 0.f, 0.f, 0.f};
    float m_ = -1e30f, ls = 0.f;   // per-lane state for q-row = li

    const int rsub = l >> 3, slot = l & 7;
    const int swzsrc = (slot * 16) ^ (rsub << 4);

    auto stage = [&](int buf, int kt) {
#pragma unroll
        for (int c = 0; c < 2; ++c) {
            int row0 = (w + c * 4) * 8;
            gload_lds16((const char*)(Kp + (size_t)(kt + row0 + rsub) * 2048) + swzsrc,
                        Ks[buf] + row0 * 128);
            gload_lds16((const char*)(Vp + (size_t)(row0 + rsub) * NTOK + kt) + swzsrc,
                        Vs[buf] + row0 * 128);
        }
    };

    const int nt = qb / 64 + 1;
    stage(0, 0);
    __syncthreads();

    char* Pw = Ps[w];
    const int rswz = (li & 7) << 4;

    for (int tt = 0; tt < nt; ++tt) {
        const int kt = tt * 64;
        const int cur = tt & 1;
        if (tt + 1 < nt) stage(cur ^ 1, kt + 64);

        // ---- QK^T, swapped operands: C[k_local][q=li] ----
        f32x4 sa[4];
#pragma unroll
        for (int ks = 0; ks < 4; ++ks) sa[ks] = (f32x4){0.f, 0.f, 0.f, 0.f};
#pragma unroll
        for (int ks = 0; ks < 4; ++ks) {
            int row = ks * 16 + li;
#pragma unroll
            for (int ds = 0; ds < 2; ++ds) {
                s16x8 kf = *(const s16x8*)(Ks[cur] + row * 128 + ((ds * 64 + g * 16) ^ rswz));
                __builtin_amdgcn_s_setprio(1);
                sa[ks] = __builtin_amdgcn_mfma_f32_16x16x32_bf16(kf, qf[ds], sa[ks], 0, 0, 0);
                __builtin_amdgcn_s_setprio(0);
            }
        }

        // ---- mask (diagonal tile only) + online softmax (exp2 domain) ----
        const bool maskt = (tt == nt - 1);
        float p[4][4];
        float pmax = -1e30f;
#pragma unroll
        for (int ks = 0; ks < 4; ++ks)
#pragma unroll
            for (int r = 0; r < 4; ++r) {
                float sv = sa[ks][r];
                if (maskt && (kt + ks * 16 + g * 4 + r > qw + li)) sv = -1e30f;
                p[ks][r] = sv;
                pmax = fmaxf(pmax, sv);
            }

        // defer-max (T13): rescale only when row max grows past threshold
        if (!__all(pmax <= m_ + 11.5f)) {
            float mx = fmaxf(pmax, __shfl_xor(pmax, 16));
            mx = fmaxf(mx, __shfl_xor(mx, 32));
            float nm = fmaxf(m_, mx);
            float fs = ex2(m_ - nm);
            m_ = nm;
            ls *= fs;
            float fsr[4];
#pragma unroll
            for (int r = 0; r < 4; ++r) fsr[r] = __shfl(fs, g * 4 + r);
#pragma unroll
            for (int d = 0; d < 4; ++d)
#pragma unroll
                for (int r = 0; r < 4; ++r) o[d][r] *= fsr[r];
        }
        float rs = 0.f;
#pragma unroll
        for (int ks = 0; ks < 4; ++ks)
#pragma unroll
            for (int r = 0; r < 4; ++r) {
                p[ks][r] = ex2(p[ks][r] - m_);
                rs += p[ks][r];
            }
        rs += __shfl_xor(rs, 16);
        rs += __shfl_xor(rs, 32);
        ls += rs;

        // ---- P -> LDS: pack 4 bf16 per ks via cvt_pk, one b64 write each ----
#pragma unroll
        for (int ks = 0; ks < 4; ++ks) {
            uint u0, u1;
            asm("v_cvt_pk_bf16_f32 %0, %1, %2" : "=v"(u0) : "v"(p[ks][0]), "v"(p[ks][1]));
            asm("v_cvt_pk_bf16_f32 %0, %1, %2" : "=v"(u1) : "v"(p[ks][2]), "v"(p[ks][3]));
            uint2 uv; uv.x = u0; uv.y = u1;
            *(uint2*)(Pw + li * 128 + ((ks * 32 + g * 8) ^ ((li & 7) << 4))) = uv;
        }

        // ---- PV: P A-frags (row=q=li) + V B-frags from swizzled LDS ----
        s16x8 pf[2];
#pragma unroll
        for (int ks2 = 0; ks2 < 2; ++ks2)
            pf[ks2] = *(const s16x8*)(Pw + li * 128 + ((ks2 * 64 + g * 16) ^ ((li & 7) << 4)));
#pragma unroll
        for (int dblk = 0; dblk < 4; ++dblk) {
            int vrow = dblk * 16 + li;
#pragma unroll
            for (int ks2 = 0; ks2 < 2; ++ks2) {
                s16x8 vf = *(const s16x8*)(Vs[cur] + vrow * 128 + ((ks2 * 64 + g * 16) ^ rswz));
                __builtin_amdgcn_s_setprio(1);
                o[dblk] = __builtin_amdgcn_mfma_f32_16x16x32_bf16(pf[ks2], vf, o[dblk], 0, 0, 0);
                __builtin_amdgcn_s_setprio(0);
            }
        }
        __syncthreads();   // drains vmcnt (stage done) + protects buffer reuse
    }

    // ---- epilogue: o[dblk][r] holds out[q=qw+g*4+r][d=dblk*16+li] ----
    float lsr[4];
#pragma unroll
    for (int r = 0; r < 4; ++r) lsr[r] = __shfl(ls, g * 4 + r);
#pragma unroll
    for (int r = 0; r < 4; ++r) {
        float inv = 1.0f / lsr[r];
        ushort* cp = ctx + (size_t)(b * SS + qw + g * 4 + r) * D_MODEL + h * DK;
#pragma unroll
        for (int dblk = 0; dblk < 4; ++dblk)
            cp[dblk * 16 + li] = f2bf(o[dblk][r] * inv);
    }
}

// ---------------------------- residual + LayerNorm -------------------------
template <bool WBF>
__global__ __launch_bounds__(256) void ln_fused(
        const float* __restrict__ xa, const float* __restrict__ xb,
        const float* __restrict__ gamma, const float* __restrict__ beta,
        float* __restrict__ outf, ushort* __restrict__ outb) {
    const int row = blockIdx.x;
    const int t   = threadIdx.x;
    const size_t off = (size_t)row * D_MODEL + t * 4;
    float4 a = *(const float4*)(xa + off);
    float4 c = *(const float4*)(xb + off);
    float z0 = a.x + c.x, z1 = a.y + c.y, z2 = a.z + c.z, z3 = a.w + c.w;
    float sum = z0 + z1 + z2 + z3;
    float sq  = z0 * z0 + z1 * z1 + z2 * z2 + z3 * z3;
#pragma unroll
    for (int o = 1; o < 64; o <<= 1) {
        sum += __shfl_xor(sum, o);
        sq  += __shfl_xor(sq, o);
    }
    __shared__ float s1[4], s2[4];
    if ((t & 63) == 0) { s1[t >> 6] = sum; s2[t >> 6] = sq; }
    __syncthreads();
    float tot = s1[0] + s1[1] + s1[2] + s1[3];
    float tsq = s2[0] + s2[1] + s2[2] + s2[3];
    const float invn = 1.0f / (float)D_MODEL;
    float mu  = tot * invn;
    float var = tsq * invn - mu * mu;
    float rstd = rsqrtf(var + 1e-5f);
    float4 gv = *(const float4*)(gamma + t * 4);
    float4 bv = *(const float4*)(beta + t * 4);
    float y0 = (z0 - mu) * rstd * gv.x + bv.x;
    float y1 = (z1 - mu) * rstd * gv.y + bv.y;
    float y2 = (z2 - mu) * rstd * gv.z + bv.z;
    float y3 = (z3 - mu) * rstd * gv.w + bv.w;
    float4 y = {y0, y1, y2, y3};
    *(float4*)(outf + off) = y;
    if constexpr (WBF) {
        ushort4 u;
        u.x = f2bf(y0); u.y = f2bf(y1); u.z = f2bf(y2); u.w = f2bf(y3);
        *(ushort4*)(outb + off) = u;
    }
}

// ---------------------------------------------------------------------------
extern "C" void kernel_launch(void* const* d_in, const int* in_sizes, int n_in,
                              void* d_out, int out_size, void* d_ws, size_t ws_size,
                              hipStream_t stream) {
    const float* x   = (const float*)d_in[0];
    const float* wq  = (const float*)d_in[2];  const float* bq  = (const float*)d_in[3];
    const float* wk  = (const float*)d_in[4];  const float* bk  = (const float*)d_in[5];
    const float* wv  = (const float*)d_in[6];  const float* bv  = (const float*)d_in[7];
    const float* wo  = (const float*)d_in[8];  const float* bo  = (const float*)d_in[9];
    const float* w1  = (const float*)d_in[10]; const float* b1  = (const float*)d_in[11];
    const float* w2  = (const float*)d_in[12]; const float* b2  = (const float*)d_in[13];
    const float* g1  = (const float*)d_in[14]; const float* be1 = (const float*)d_in[15];
    const float* g2  = (const float*)d_in[16]; const float* be2 = (const float*)d_in[17];
    float* out = (float*)d_out;

    char* ws = (char*)d_ws;
    const size_t MB = 1u << 20;
    ushort* wqkb = (ushort*)(ws + 0 * MB);    // [2048][1024] bf16 (wq then wk)
    ushort* wvb  = (ushort*)(ws + 4 * MB);
    ushort* wob  = (ushort*)(ws + 6 * MB);
    ushort* w1b  = (ushort*)(ws + 8 * MB);
    ushort* w2b  = (ushort*)(ws + 16 * MB);
    ushort* xb   = (ushort*)(ws + 24 * MB);
    ushort* QKb  = (ushort*)(ws + 32 * MB);   // [4096][2048] bf16
    ushort* VtG  = (ushort*)(ws + 48 * MB);   // [1024][4096] bf16
    ushort* ctx  = (ushort*)(ws + 56 * MB);
    float*  tmpf = (float*)(ws + 64 * MB);
    float*  h    = (float*)(ws + 80 * MB);
    ushort* hb   = (ushort*)(ws + 96 * MB);
    ushort* ffib = (ushort*)(ws + 104 * MB);  // -> 136MB total

    auto cvt = [&](const float* s, ushort* d, int n) {
        cvt_kernel<<<dim3(n / 1024), dim3(256), 0, stream>>>(s, d, n);
    };
    cvt(wq, wqkb,                     D_MODEL * D_MODEL);
    cvt(wk, wqkb + D_MODEL * D_MODEL, D_MODEL * D_MODEL);
    cvt(wv, wvb, D_MODEL * D_MODEL);
    cvt(wo, wob, D_MODEL * D_MODEL);
    cvt(w1, w1b, D_FF * D_MODEL);
    cvt(w2, w2b, D_MODEL * D_FF);
    cvt(x,  xb,  NTOK * D_MODEL);

    dim3 blk(256);
    // fused Q,K projection: [4096][2048]; Q columns pre-scaled by QSCALE
    gemm_bt<false, true, false, true><<<dim3(16 * 32), blk, 0, stream>>>(
        xb, wqkb, bq, bk, D_MODEL, QKb, NTOK, 2 * D_MODEL, D_MODEL, 16);
    // V^T = Wv * X^T : [1024][4096], bias per row
    gemm_bt<false, true, true, false><<<dim3(32 * 8), blk, 0, stream>>>(
        wvb, xb, bv, bv, 0, VtG, D_MODEL, NTOK, D_MODEL, 32);

    attn_kernel<<<dim3(SS / 64, 16, BB), dim3(256), 0, stream>>>(QKb, VtG, ctx);

    gemm_bt<false, false, false, false><<<dim3(8 * 32), blk, 0, stream>>>(
        ctx, wob, bo, bo, D_MODEL, tmpf, NTOK, D_MODEL, D_MODEL, 8);
    ln_fused<true><<<dim3(NTOK), blk, 0, stream>>>(x, tmpf, g1, be1, h, hb);
    gemm_bt<true, true, false, false><<<dim3(32 * 32), blk, 0, stream>>>(
        hb, w1b, b1, b1, D_FF, ffib, NTOK, D_FF, D_MODEL, 32);
    gemm_bt<false, false, false, false><<<dim3(8 * 32), blk, 0, stream>>>(
        ffib, w2b, b2, b2, D_MODEL, tmpf, NTOK, D_MODEL, D_FF, 8);
    ln_fused<false><<<dim3(NTOK), blk, 0, stream>>>(h, tmpf, g2, be2, out, nullptr);
}

// Round 6
// 253.734 us; speedup vs baseline: 1.0955x; 1.0955x over previous
//
#include <hip/hip_runtime.h>
#include <hip/hip_bf16.h>

// ---------------------------------------------------------------------------
// TransformerBlock: x[2,2048,1024] fp32 -> out fp32
// bf16 MFMA GEMMs (dbuf global_load_lds staging, XCD swizzle, split-K via
// fused-partials in LayerNorm) + swapped-QK^T flash attention.
// ---------------------------------------------------------------------------

using f32x4 = __attribute__((ext_vector_type(4))) float;
using s16x8 = __attribute__((ext_vector_type(8))) short;

constexpr int D_MODEL = 1024;
constexpr int D_FF    = 4096;
constexpr int DK      = 64;
constexpr int BB      = 2;
constexpr int SS      = 2048;
constexpr int NTOK    = BB * SS;   // 4096

// 0.125 (1/sqrt(dk)) * log2(e): folded into Q at the QK-projection epilogue.
#define QSCALE 0.18033688011112042f

__device__ __forceinline__ ushort f2bf(float f) {
    unsigned u = __float_as_uint(f);
    u += 0x7fffu + ((u >> 16) & 1u);   // round-to-nearest-even
    return (ushort)(u >> 16);
}

__device__ __forceinline__ float ex2(float x) {
    float r;
    asm("v_exp_f32 %0, %1" : "=v"(r) : "v"(x));
    return r;
}

__device__ __forceinline__ void gload_lds16(const void* g, void* l) {
    __builtin_amdgcn_global_load_lds(
        (const __attribute__((address_space(1))) void*)g,
        (__attribute__((address_space(3))) void*)l, 16, 0, 0);
}

// ---------------------- fused fp32 -> bf16 convert (7 segments) ------------
struct CvtArgs { const float* src[7]; ushort* dst[7]; };

__global__ __launch_bounds__(256) void cvt_all(CvtArgs a) {
    // segment starts in M-elements: wq,wk,wv,wo (1M each), w1,w2,x (4M each)
    constexpr long S[8] = {0L<<20, 1L<<20, 2L<<20, 3L<<20,
                           4L<<20, 8L<<20, 12L<<20, 16L<<20};
    long i = ((long)blockIdx.x * 256 + threadIdx.x) * 4;
    int s = 0;
#pragma unroll
    for (int j = 1; j < 7; ++j) if (i >= S[j]) s = j;
    long off = i - S[s];
    float4 v = *(const float4*)(a.src[s] + off);
    ushort4 o;
    o.x = f2bf(v.x); o.y = f2bf(v.y); o.z = f2bf(v.z); o.w = f2bf(v.w);
    *(ushort4*)(a.dst[s] + off) = o;
}

// ---------------------------- GEMM: C = A * W^T + bias ---------------------
// A: [M,ldk] bf16. W: [N,ldk] bf16. C: [M,N] fp32 or bf16.
// 128x128 tile, BK=64, 4 waves (2x2), each wave 64x64 via 4x4 16x16x32 frags.
// Double-buffered LDS, one __syncthreads per K-step (T3 minimum 2-phase).
// splitk>1: single launch, s = tile-index / (gx*gy); partial s goes to
// Cout + s*M*N (fp32), K-range [s*Klen, (s+1)*Klen); bias only in s==0.
template <bool RELU, bool OUTBF16, bool BIASROW, bool SCALEQ>
__global__ __launch_bounds__(256, 2) void gemm_bt(
        const ushort* __restrict__ A, const ushort* __restrict__ W,
        const float* __restrict__ bias, const float* __restrict__ bias2, int nsplit,
        void* __restrict__ Cout, int M, int N, int Klen, int ldk, int gx, int splitk) {
    __shared__ __align__(16) char Asb[2][128 * 128];
    __shared__ __align__(16) char Bsb[2][128 * 128];

    const int nwg = (int)gridDim.x;
    const int id  = (int)blockIdx.x;
    const int sw  = (id & 7) * (nwg >> 3) + (id >> 3);   // XCD-chunked swizzle
    const int tps = nwg / splitk;
    const int s   = sw / tps;
    const int rem = sw - s * tps;
    const int bx  = rem % gx, by = rem / gx;

    const int t  = threadIdx.x;
    const int l  = t & 63;
    const int w  = t >> 6;
    const int wr = w >> 1, wc = w & 1;
    const int li = l & 15, g = l >> 4;
    const int bm0 = by << 7;
    const int bn0 = bx << 7;
    const int kbase = s * Klen;

    f32x4 acc[4][4];
#pragma unroll
    for (int m = 0; m < 4; ++m)
#pragma unroll
        for (int n = 0; n < 4; ++n)
            acc[m][n] = (f32x4){0.f, 0.f, 0.f, 0.f};

    const int rsub = l >> 3, slot = l & 7;
    const int swzel = (((slot * 16) ^ (rsub << 4)) >> 1);   // element offset in 64-chunk

    auto stage = [&](int buf, int k0) {
#pragma unroll
        for (int i = 0; i < 4; ++i) {
            const int rbase = i * 32 + w * 8;   // wave-uniform LDS dest base
            gload_lds16(A + (size_t)(bm0 + rbase + rsub) * ldk + kbase + k0 + swzel,
                        Asb[buf] + rbase * 128);
            gload_lds16(W + (size_t)(bn0 + rbase + rsub) * ldk + kbase + k0 + swzel,
                        Bsb[buf] + rbase * 128);
        }
    };

    const int nk = Klen >> 6;
    stage(0, 0);
    __syncthreads();

    for (int tt = 0; tt < nk; ++tt) {
        const int cur = tt & 1;
        if (tt + 1 < nk) stage(cur ^ 1, (tt + 1) << 6);
#pragma unroll
        for (int ks = 0; ks < 2; ++ks) {
            s16x8 af[4], bfr[4];
#pragma unroll
            for (int m = 0; m < 4; ++m) {
                int row = wr * 64 + m * 16 + li;
                af[m] = *(const s16x8*)(Asb[cur] + row * 128 + (((ks * 4 + g) * 16) ^ ((row & 7) << 4)));
            }
#pragma unroll
            for (int n = 0; n < 4; ++n) {
                int row = wc * 64 + n * 16 + li;
                bfr[n] = *(const s16x8*)(Bsb[cur] + row * 128 + (((ks * 4 + g) * 16) ^ ((row & 7) << 4)));
            }
            __builtin_amdgcn_s_setprio(1);
#pragma unroll
            for (int m = 0; m < 4; ++m)
#pragma unroll
                for (int n = 0; n < 4; ++n)
                    acc[m][n] = __builtin_amdgcn_mfma_f32_16x16x32_bf16(af[m], bfr[n], acc[m][n], 0, 0, 0);
            __builtin_amdgcn_s_setprio(0);
        }
        __syncthreads();   // drains stage's vmcnt + protects buffer reuse
    }

    const float* bptr = (s == 0) ? bias : nullptr;
    float* Cf = (float*)Cout + (size_t)s * M * N;
#pragma unroll
    for (int m = 0; m < 4; ++m) {
        int row0 = bm0 + wr * 64 + m * 16 + g * 4;
#pragma unroll
        for (int n = 0; n < 4; ++n) {
            int col = bn0 + wc * 64 + n * 16 + li;
            float bsv = 0.f;
            if (!BIASROW && bptr) bsv = (col < nsplit) ? bptr[col] : bias2[col - nsplit];
#pragma unroll
            for (int r = 0; r < 4; ++r) {
                float v = acc[m][n][r] + (BIASROW ? (bptr ? bptr[row0 + r] : 0.f) : bsv);
                if (RELU) v = fmaxf(v, 0.f);
                if (SCALEQ && col < nsplit) v *= QSCALE;   // pre-scale Q for exp2 softmax
                size_t idx = (size_t)(row0 + r) * N + col;
                if (OUTBF16) ((ushort*)Cout)[idx] = f2bf(v);
                else         Cf[idx] = v;
            }
        }
    }
}

// ---------------------------- causal flash attention -----------------------
// QKb: [NTOK][2048] bf16 (Q pre-scaled by QSCALE at col h*64, K at 1024+h*64).
// VtG: [1024][NTOK] bf16 == V^T.
// Block = 4 waves = 64 Q rows of one (b,h); swapped QK^T (lane-local softmax).
__global__ __launch_bounds__(256, 4) void attn_kernel(
        const ushort* __restrict__ QKb, const ushort* __restrict__ VtG,
        ushort* __restrict__ ctx) {
    __shared__ __align__(16) char Ks[2][64 * 128];
    __shared__ __align__(16) char Vs[2][64 * 128];
    __shared__ __align__(16) char Ps[4][16 * 128];

    const int t  = threadIdx.x;
    const int l  = t & 63;
    const int w  = t >> 6;
    const int li = l & 15, g = l >> 4;
    const int qb = ((int)gridDim.x - 1 - (int)blockIdx.x) * 64;  // big blocks first
    const int h  = blockIdx.y;
    const int b  = blockIdx.z;
    const int qw = qb + w * 16;

    const ushort* Qp = QKb + (size_t)(b * SS + qw) * 2048 + h * DK;
    const ushort* Kp = QKb + (size_t)(b * SS) * 2048 + 1024 + h * DK;
    const ushort* Vp = VtG + (size_t)(h * DK) * NTOK + b * SS;

    s16x8 qf[2];
#pragma unroll
    for (int ds = 0; ds < 2; ++ds)
        qf[ds] = *(const s16x8*)(Qp + li * 2048 + ds * 32 + g * 8);

    f32x4 o[4];
#pragma unroll
    for (int d = 0; d < 4; ++d) o[d] = (f32x4){0.f, 0.f, 0.f, 0.f};
    float m_ = -1e30f, ls = 0.f;   // per-lane state for q-row = li

    const int rsub = l >> 3, slot = l & 7;
    const int swzsrc = (slot * 16) ^ (rsub << 4);

    auto stage = [&](int buf, int kt) {
#pragma unroll
        for (int c = 0; c < 2; ++c) {
            int row0 = (w + c * 4) * 8;
            gload_lds16((const char*)(Kp + (size_t)(kt + row0 + rsub) * 2048) + swzsrc,
                        Ks[buf] + row0 * 128);
            gload_lds16((const char*)(Vp + (size_t)(row0 + rsub) * NTOK + kt) + swzsrc,
                        Vs[buf] + row0 * 128);
        }
    };

    const int nt = qb / 64 + 1;
    stage(0, 0);
    __syncthreads();

    char* Pw = Ps[w];
    const int rswz = (li & 7) << 4;

    for (int tt = 0; tt < nt; ++tt) {
        const int kt = tt * 64;
        const int cur = tt & 1;
        if (tt + 1 < nt) stage(cur ^ 1, kt + 64);

        // ---- QK^T, swapped operands: C[k_local][q=li] ----
        f32x4 sa[4];
#pragma unroll
        for (int ks = 0; ks < 4; ++ks) sa[ks] = (f32x4){0.f, 0.f, 0.f, 0.f};
#pragma unroll
        for (int ks = 0; ks < 4; ++ks) {
            int row = ks * 16 + li;
#pragma unroll
            for (int ds = 0; ds < 2; ++ds) {
                s16x8 kf = *(const s16x8*)(Ks[cur] + row * 128 + ((ds * 64 + g * 16) ^ rswz));
                __builtin_amdgcn_s_setprio(1);
                sa[ks] = __builtin_amdgcn_mfma_f32_16x16x32_bf16(kf, qf[ds], sa[ks], 0, 0, 0);
                __builtin_amdgcn_s_setprio(0);
            }
        }

        // ---- mask (diagonal tile only) + online softmax (exp2 domain) ----
        const bool maskt = (tt == nt - 1);
        float p[4][4];
        float pmax = -1e30f;
#pragma unroll
        for (int ks = 0; ks < 4; ++ks)
#pragma unroll
            for (int r = 0; r < 4; ++r) {
                float sv = sa[ks][r];
                if (maskt && (kt + ks * 16 + g * 4 + r > qw + li)) sv = -1e30f;
                p[ks][r] = sv;
                pmax = fmaxf(pmax, sv);
            }

        // defer-max (T13): rescale only when row max grows past threshold
        if (!__all(pmax <= m_ + 11.5f)) {
            float mx = fmaxf(pmax, __shfl_xor(pmax, 16));
            mx = fmaxf(mx, __shfl_xor(mx, 32));
            float nm = fmaxf(m_, mx);
            float fs = ex2(m_ - nm);
            m_ = nm;
            ls *= fs;
            float fsr[4];
#pragma unroll
            for (int r = 0; r < 4; ++r) fsr[r] = __shfl(fs, g * 4 + r);
#pragma unroll
            for (int d = 0; d < 4; ++d)
#pragma unroll
                for (int r = 0; r < 4; ++r) o[d][r] *= fsr[r];
        }
        float rs = 0.f;
#pragma unroll
        for (int ks = 0; ks < 4; ++ks)
#pragma unroll
            for (int r = 0; r < 4; ++r) {
                p[ks][r] = ex2(p[ks][r] - m_);
                rs += p[ks][r];
            }
        rs += __shfl_xor(rs, 16);
        rs += __shfl_xor(rs, 32);
        ls += rs;

        // ---- P -> LDS: pack 4 bf16 per ks via cvt_pk, one b64 write each ----
#pragma unroll
        for (int ks = 0; ks < 4; ++ks) {
            uint u0, u1;
            asm("v_cvt_pk_bf16_f32 %0, %1, %2" : "=v"(u0) : "v"(p[ks][0]), "v"(p[ks][1]));
            asm("v_cvt_pk_bf16_f32 %0, %1, %2" : "=v"(u1) : "v"(p[ks][2]), "v"(p[ks][3]));
            uint2 uv; uv.x = u0; uv.y = u1;
            *(uint2*)(Pw + li * 128 + ((ks * 32 + g * 8) ^ ((li & 7) << 4))) = uv;
        }

        // ---- PV: P A-frags (row=q=li) + V B-frags from swizzled LDS ----
        s16x8 pf[2];
#pragma unroll
        for (int ks2 = 0; ks2 < 2; ++ks2)
            pf[ks2] = *(const s16x8*)(Pw + li * 128 + ((ks2 * 64 + g * 16) ^ ((li & 7) << 4)));
#pragma unroll
        for (int dblk = 0; dblk < 4; ++dblk) {
            int vrow = dblk * 16 + li;
#pragma unroll
            for (int ks2 = 0; ks2 < 2; ++ks2) {
                s16x8 vf = *(const s16x8*)(Vs[cur] + vrow * 128 + ((ks2 * 64 + g * 16) ^ rswz));
                __builtin_amdgcn_s_setprio(1);
                o[dblk] = __builtin_amdgcn_mfma_f32_16x16x32_bf16(pf[ks2], vf, o[dblk], 0, 0, 0);
                __builtin_amdgcn_s_setprio(0);
            }
        }
        __syncthreads();   // drains vmcnt (stage done) + protects buffer reuse
    }

    // ---- epilogue: o[dblk][r] holds out[q=qw+g*4+r][d=dblk*16+li] ----
    float lsr[4];
#pragma unroll
    for (int r = 0; r < 4; ++r) lsr[r] = __shfl(ls, g * 4 + r);
#pragma unroll
    for (int r = 0; r < 4; ++r) {
        float inv = 1.0f / lsr[r];
        ushort* cp = ctx + (size_t)(b * SS + qw + g * 4 + r) * D_MODEL + h * DK;
#pragma unroll
        for (int dblk = 0; dblk < 4; ++dblk)
            cp[dblk * 16 + li] = f2bf(o[dblk][r] * inv);
    }
}

// ------------------- residual (+split-K partials) + LayerNorm --------------
// z = xa + xb (+ xc if X3): xb/xc are the two split-K partial outputs.
template <bool WBF, bool X3>
__global__ __launch_bounds__(256) void ln_fused(
        const float* __restrict__ xa, const float* __restrict__ xb,
        const float* __restrict__ xc,
        const float* __restrict__ gamma, const float* __restrict__ beta,
        float* __restrict__ outf, ushort* __restrict__ outb) {
    const int row = blockIdx.x;
    const int t   = threadIdx.x;
    const size_t off = (size_t)row * D_MODEL + t * 4;
    float4 a = *(const float4*)(xa + off);
    float4 c = *(const float4*)(xb + off);
    float z0 = a.x + c.x, z1 = a.y + c.y, z2 = a.z + c.z, z3 = a.w + c.w;
    if constexpr (X3) {
        float4 d = *(const float4*)(xc + off);
        z0 += d.x; z1 += d.y; z2 += d.z; z3 += d.w;
    }
    float sum = z0 + z1 + z2 + z3;
    float sq  = z0 * z0 + z1 * z1 + z2 * z2 + z3 * z3;
#pragma unroll
    for (int o = 1; o < 64; o <<= 1) {
        sum += __shfl_xor(sum, o);
        sq  += __shfl_xor(sq, o);
    }
    __shared__ float s1[4], s2[4];
    if ((t & 63) == 0) { s1[t >> 6] = sum; s2[t >> 6] = sq; }
    __syncthreads();
    float tot = s1[0] + s1[1] + s1[2] + s1[3];
    float tsq = s2[0] + s2[1] + s2[2] + s2[3];
    const float invn = 1.0f / (float)D_MODEL;
    float mu  = tot * invn;
    float var = tsq * invn - mu * mu;
    float rstd = rsqrtf(var + 1e-5f);
    float4 gv = *(const float4*)(gamma + t * 4);
    float4 bv = *(const float4*)(beta + t * 4);
    float y0 = (z0 - mu) * rstd * gv.x + bv.x;
    float y1 = (z1 - mu) * rstd * gv.y + bv.y;
    float y2 = (z2 - mu) * rstd * gv.z + bv.z;
    float y3 = (z3 - mu) * rstd * gv.w + bv.w;
    float4 y = {y0, y1, y2, y3};
    *(float4*)(outf + off) = y;
    if constexpr (WBF) {
        ushort4 u;
        u.x = f2bf(y0); u.y = f2bf(y1); u.z = f2bf(y2); u.w = f2bf(y3);
        *(ushort4*)(outb + off) = u;
    }
}

// ---------------------------------------------------------------------------
extern "C" void kernel_launch(void* const* d_in, const int* in_sizes, int n_in,
                              void* d_out, int out_size, void* d_ws, size_t ws_size,
                              hipStream_t stream) {
    const float* x   = (const float*)d_in[0];
    const float* wq  = (const float*)d_in[2];  const float* bq  = (const float*)d_in[3];
    const float* wk  = (const float*)d_in[4];  const float* bk  = (const float*)d_in[5];
    const float* wv  = (const float*)d_in[6];  const float* bv  = (const float*)d_in[7];
    const float* wo  = (const float*)d_in[8];  const float* bo  = (const float*)d_in[9];
    const float* w1  = (const float*)d_in[10]; const float* b1  = (const float*)d_in[11];
    const float* w2  = (const float*)d_in[12]; const float* b2  = (const float*)d_in[13];
    const float* g1  = (const float*)d_in[14]; const float* be1 = (const float*)d_in[15];
    const float* g2  = (const float*)d_in[16]; const float* be2 = (const float*)d_in[17];
    float* out = (float*)d_out;

    char* ws = (char*)d_ws;
    const size_t MB = 1u << 20;
    ushort* wqkb = (ushort*)(ws + 0 * MB);    // [2048][1024] bf16 (wq then wk)
    ushort* wvb  = (ushort*)(ws + 4 * MB);
    ushort* wob  = (ushort*)(ws + 6 * MB);
    ushort* w1b  = (ushort*)(ws + 8 * MB);
    ushort* w2b  = (ushort*)(ws + 16 * MB);
    ushort* xb   = (ushort*)(ws + 24 * MB);   // dead after Vt GEMM
    ushort* QKb  = (ushort*)(ws + 32 * MB);   // [4096][2048]; dead after attn
    ushort* VtG  = (ushort*)(ws + 48 * MB);   // [1024][4096]; dead after attn
    ushort* ctx  = (ushort*)(ws + 56 * MB);   // dead after O-proj
    float*  p0   = (float*)(ws + 64 * MB);    // split-K partial 0 (16MB)
    float*  p1   = (float*)(ws + 80 * MB);    // split-K partial 1 (16MB)
    float*  h    = (float*)(ws + 96 * MB);
    ushort* hb   = (ushort*)(ws + 112 * MB);
    ushort* ffib = (ushort*)(ws + 24 * MB);   // 32MB, reuses xb+QKb (both dead)
    // peak usage: 120 MB

    CvtArgs ca;
    ca.src[0] = wq; ca.dst[0] = wqkb;
    ca.src[1] = wk; ca.dst[1] = wqkb + D_MODEL * D_MODEL;
    ca.src[2] = wv; ca.dst[2] = wvb;
    ca.src[3] = wo; ca.dst[3] = wob;
    ca.src[4] = w1; ca.dst[4] = w1b;
    ca.src[5] = w2; ca.dst[5] = w2b;
    ca.src[6] = x;  ca.dst[6] = xb;
    cvt_all<<<dim3(16384), dim3(256), 0, stream>>>(ca);

    dim3 blk(256);
    // fused Q,K projection: [4096][2048]; Q columns pre-scaled by QSCALE
    gemm_bt<false, true, false, true><<<dim3(512), blk, 0, stream>>>(
        xb, wqkb, bq, bk, D_MODEL, QKb, NTOK, 2 * D_MODEL, D_MODEL, D_MODEL, 16, 1);
    // V^T = Wv * X^T : [1024][4096], bias per row
    gemm_bt<false, true, true, false><<<dim3(256), blk, 0, stream>>>(
        wvb, xb, bv, bv, 0, VtG, D_MODEL, NTOK, D_MODEL, D_MODEL, 32, 1);

    attn_kernel<<<dim3(SS / 64, 16, BB), dim3(256), 0, stream>>>(QKb, VtG, ctx);

    // O projection, split-K x2 (one launch, 512 blocks): partials p0,p1
    gemm_bt<false, false, false, false><<<dim3(512), blk, 0, stream>>>(
        ctx, wob, bo, bo, D_MODEL, p0, NTOK, D_MODEL, 512, D_MODEL, 8, 2);
    ln_fused<true, true><<<dim3(NTOK), blk, 0, stream>>>(x, p0, p1, g1, be1, h, hb);

    gemm_bt<true, true, false, false><<<dim3(1024), blk, 0, stream>>>(
        hb, w1b, b1, b1, D_FF, ffib, NTOK, D_FF, D_MODEL, D_MODEL, 32, 1);
    // FFN2, split-K x2 (one launch, 512 blocks): partials p0,p1
    gemm_bt<false, false, false, false><<<dim3(512), blk, 0, stream>>>(
        ffib, w2b, b2, b2, D_MODEL, p0, NTOK, D_MODEL, 2048, D_FF, 8, 2);
    ln_fused<false, true><<<dim3(NTOK), blk, 0, stream>>>(h, p0, p1, g2, be2, out, nullptr);
}

// Round 7
// 247.991 us; speedup vs baseline: 1.1209x; 1.0232x over previous
//
#include <hip/hip_runtime.h>
#include <hip/hip_bf16.h>

// ---------------------------------------------------------------------------
// TransformerBlock: x[2,2048,1024] fp32 -> out fp32
// bf16 MFMA GEMMs (dbuf global_load_lds staging, XCD swizzle, split-K via
// fused-partials in LayerNorm) + swapped-QK^T flash attention with
// pair-balanced causal stripes (block bx does stripes 31-bx and bx: 33 tiles).
// ---------------------------------------------------------------------------

using f32x4 = __attribute__((ext_vector_type(4))) float;
using s16x8 = __attribute__((ext_vector_type(8))) short;

constexpr int D_MODEL = 1024;
constexpr int D_FF    = 4096;
constexpr int DK      = 64;
constexpr int BB      = 2;
constexpr int SS      = 2048;
constexpr int NTOK    = BB * SS;   // 4096

// 0.125 (1/sqrt(dk)) * log2(e): folded into Q at the QK-projection epilogue.
#define QSCALE 0.18033688011112042f

__device__ __forceinline__ ushort f2bf(float f) {
    unsigned u = __float_as_uint(f);
    u += 0x7fffu + ((u >> 16) & 1u);   // round-to-nearest-even
    return (ushort)(u >> 16);
}

__device__ __forceinline__ float ex2(float x) {
    float r;
    asm("v_exp_f32 %0, %1" : "=v"(r) : "v"(x));
    return r;
}

__device__ __forceinline__ void gload_lds16(const void* g, void* l) {
    __builtin_amdgcn_global_load_lds(
        (const __attribute__((address_space(1))) void*)g,
        (__attribute__((address_space(3))) void*)l, 16, 0, 0);
}

// ---------------------- fused fp32 -> bf16 convert (7 segments) ------------
struct CvtArgs { const float* src[7]; ushort* dst[7]; };

__global__ __launch_bounds__(256) void cvt_all(CvtArgs a) {
    // segment starts in M-elements: wq,wk,wv,wo (1M each), w1,w2,x (4M each)
    constexpr long S[8] = {0L<<20, 1L<<20, 2L<<20, 3L<<20,
                           4L<<20, 8L<<20, 12L<<20, 16L<<20};
    long i = ((long)blockIdx.x * 256 + threadIdx.x) * 4;
    int s = 0;
#pragma unroll
    for (int j = 1; j < 7; ++j) if (i >= S[j]) s = j;
    long off = i - S[s];
    float4 v = *(const float4*)(a.src[s] + off);
    ushort4 o;
    o.x = f2bf(v.x); o.y = f2bf(v.y); o.z = f2bf(v.z); o.w = f2bf(v.w);
    *(ushort4*)(a.dst[s] + off) = o;
}

// ---------------------------- GEMM: C = A * W^T + bias ---------------------
// A: [M,ldk] bf16. W: [N,ldk] bf16. C: [M,N] fp32 or bf16.
// 128x128 tile, BK=64, 4 waves (2x2), each wave 64x64 via 4x4 16x16x32 frags.
// Double-buffered LDS, one __syncthreads per K-step (T3 minimum 2-phase).
// splitk>1: partial s -> Cout + s*M*N (fp32), K-range [s*Klen,(s+1)*Klen).
template <bool RELU, bool OUTBF16, bool BIASROW, bool SCALEQ>
__global__ __launch_bounds__(256, 2) void gemm_bt(
        const ushort* __restrict__ A, const ushort* __restrict__ W,
        const float* __restrict__ bias, const float* __restrict__ bias2, int nsplit,
        void* __restrict__ Cout, int M, int N, int Klen, int ldk, int gx, int splitk) {
    __shared__ __align__(16) char Asb[2][128 * 128];
    __shared__ __align__(16) char Bsb[2][128 * 128];

    const int nwg = (int)gridDim.x;
    const int id  = (int)blockIdx.x;
    const int sw  = (id & 7) * (nwg >> 3) + (id >> 3);   // XCD-chunked swizzle
    const int tps = nwg / splitk;
    const int s   = sw / tps;
    const int rem = sw - s * tps;
    const int bx  = rem % gx, by = rem / gx;

    const int t  = threadIdx.x;
    const int l  = t & 63;
    const int w  = t >> 6;
    const int wr = w >> 1, wc = w & 1;
    const int li = l & 15, g = l >> 4;
    const int bm0 = by << 7;
    const int bn0 = bx << 7;
    const int kbase = s * Klen;

    f32x4 acc[4][4];
#pragma unroll
    for (int m = 0; m < 4; ++m)
#pragma unroll
        for (int n = 0; n < 4; ++n)
            acc[m][n] = (f32x4){0.f, 0.f, 0.f, 0.f};

    const int rsub = l >> 3, slot = l & 7;
    const int swzel = (((slot * 16) ^ (rsub << 4)) >> 1);   // element offset in 64-chunk

    auto stage = [&](int buf, int k0) {
#pragma unroll
        for (int i = 0; i < 4; ++i) {
            const int rbase = i * 32 + w * 8;   // wave-uniform LDS dest base
            gload_lds16(A + (size_t)(bm0 + rbase + rsub) * ldk + kbase + k0 + swzel,
                        Asb[buf] + rbase * 128);
            gload_lds16(W + (size_t)(bn0 + rbase + rsub) * ldk + kbase + k0 + swzel,
                        Bsb[buf] + rbase * 128);
        }
    };

    const int nk = Klen >> 6;
    stage(0, 0);
    __syncthreads();

    for (int tt = 0; tt < nk; ++tt) {
        const int cur = tt & 1;
        if (tt + 1 < nk) stage(cur ^ 1, (tt + 1) << 6);
#pragma unroll
        for (int ks = 0; ks < 2; ++ks) {
            s16x8 af[4], bfr[4];
#pragma unroll
            for (int m = 0; m < 4; ++m) {
                int row = wr * 64 + m * 16 + li;
                af[m] = *(const s16x8*)(Asb[cur] + row * 128 + (((ks * 4 + g) * 16) ^ ((row & 7) << 4)));
            }
#pragma unroll
            for (int n = 0; n < 4; ++n) {
                int row = wc * 64 + n * 16 + li;
                bfr[n] = *(const s16x8*)(Bsb[cur] + row * 128 + (((ks * 4 + g) * 16) ^ ((row & 7) << 4)));
            }
            __builtin_amdgcn_s_setprio(1);
#pragma unroll
            for (int m = 0; m < 4; ++m)
#pragma unroll
                for (int n = 0; n < 4; ++n)
                    acc[m][n] = __builtin_amdgcn_mfma_f32_16x16x32_bf16(af[m], bfr[n], acc[m][n], 0, 0, 0);
            __builtin_amdgcn_s_setprio(0);
        }
        __syncthreads();   // drains stage's vmcnt + protects buffer reuse
    }

    const float* bptr = (s == 0) ? bias : nullptr;
    float* Cf = (float*)Cout + (size_t)s * M * N;
#pragma unroll
    for (int m = 0; m < 4; ++m) {
        int row0 = bm0 + wr * 64 + m * 16 + g * 4;
#pragma unroll
        for (int n = 0; n < 4; ++n) {
            int col = bn0 + wc * 64 + n * 16 + li;
            float bsv = 0.f;
            if (!BIASROW && bptr) bsv = (col < nsplit) ? bptr[col] : bias2[col - nsplit];
#pragma unroll
            for (int r = 0; r < 4; ++r) {
                float v = acc[m][n][r] + (BIASROW ? (bptr ? bptr[row0 + r] : 0.f) : bsv);
                if (RELU) v = fmaxf(v, 0.f);
                if (SCALEQ && col < nsplit) v *= QSCALE;   // pre-scale Q for exp2 softmax
                size_t idx = (size_t)(row0 + r) * N + col;
                if (OUTBF16) ((ushort*)Cout)[idx] = f2bf(v);
                else         Cf[idx] = v;
            }
        }
    }
}

// ---------------------------- causal flash attention -----------------------
// QKb: [NTOK][2048] bf16 (Q pre-scaled by QSCALE at col h*64, K at 1024+h*64).
// VtG: [1024][NTOK] bf16 == V^T.
// Pair-balanced: block bx in [0,16) processes stripe (31-bx) then stripe bx
// of one (b,h) -> exactly 33 staged tiles per block, no causal tail.
// Swapped QK^T (lane-local softmax), dbuf XOR-swizzled LDS staging.
__global__ __launch_bounds__(256, 4) void attn_kernel(
        const ushort* __restrict__ QKb, const ushort* __restrict__ VtG,
        ushort* __restrict__ ctx) {
    __shared__ __align__(16) char Ks[2][64 * 128];
    __shared__ __align__(16) char Vs[2][64 * 128];
    __shared__ __align__(16) char Ps[4][16 * 128];

    const int t  = threadIdx.x;
    const int l  = t & 63;
    const int w  = t >> 6;
    const int li = l & 15, g = l >> 4;
    const int bx = (int)blockIdx.x;          // 0..15
    const int h  = blockIdx.y;
    const int b  = blockIdx.z;

    const ushort* Kp = QKb + (size_t)(b * SS) * 2048 + 1024 + h * DK;
    const ushort* Vp = VtG + (size_t)(h * DK) * NTOK + b * SS;

    const int rsub = l >> 3, slot = l & 7;
    const int swzsrc = (slot * 16) ^ (rsub << 4);

    auto stage = [&](int buf, int kt) {
#pragma unroll
        for (int c = 0; c < 2; ++c) {
            int row0 = (w + c * 4) * 8;
            gload_lds16((const char*)(Kp + (size_t)(kt + row0 + rsub) * 2048) + swzsrc,
                        Ks[buf] + row0 * 128);
            gload_lds16((const char*)(Vp + (size_t)(row0 + rsub) * NTOK + kt) + swzsrc,
                        Vs[buf] + row0 * 128);
        }
    };

    char* Pw = Ps[w];
    const int rswz = (li & 7) << 4;

    for (int ss = 0; ss < 2; ++ss) {
        const int stripe = ss ? bx : (SS / 64 - 1 - bx);
        const int qb = stripe * 64;
        const int qw = qb + w * 16;

        const ushort* Qp = QKb + (size_t)(b * SS + qw) * 2048 + h * DK;
        s16x8 qf[2];
#pragma unroll
        for (int ds = 0; ds < 2; ++ds)
            qf[ds] = *(const s16x8*)(Qp + li * 2048 + ds * 32 + g * 8);

        f32x4 o[4];
#pragma unroll
        for (int d = 0; d < 4; ++d) o[d] = (f32x4){0.f, 0.f, 0.f, 0.f};
        float m_ = -1e30f, ls = 0.f;   // per-lane state for q-row = li

        const int nt = stripe + 1;
        stage(0, 0);
        __syncthreads();

        for (int tt = 0; tt < nt; ++tt) {
            const int kt = tt * 64;
            const int cur = tt & 1;
            if (tt + 1 < nt) stage(cur ^ 1, kt + 64);

            // ---- QK^T, swapped operands: C[k_local][q=li] ----
            f32x4 sa[4];
#pragma unroll
            for (int ks = 0; ks < 4; ++ks) sa[ks] = (f32x4){0.f, 0.f, 0.f, 0.f};
#pragma unroll
            for (int ks = 0; ks < 4; ++ks) {
                int row = ks * 16 + li;
#pragma unroll
                for (int ds = 0; ds < 2; ++ds) {
                    s16x8 kf = *(const s16x8*)(Ks[cur] + row * 128 + ((ds * 64 + g * 16) ^ rswz));
                    __builtin_amdgcn_s_setprio(1);
                    sa[ks] = __builtin_amdgcn_mfma_f32_16x16x32_bf16(kf, qf[ds], sa[ks], 0, 0, 0);
                    __builtin_amdgcn_s_setprio(0);
                }
            }

            // ---- mask (diagonal tile only) + online softmax (exp2 domain) ----
            const bool maskt = (tt == nt - 1);
            float p[4][4];
            float pmax = -1e30f;
#pragma unroll
            for (int ks = 0; ks < 4; ++ks)
#pragma unroll
                for (int r = 0; r < 4; ++r) {
                    float sv = sa[ks][r];
                    if (maskt && (kt + ks * 16 + g * 4 + r > qw + li)) sv = -1e30f;
                    p[ks][r] = sv;
                    pmax = fmaxf(pmax, sv);
                }

            // defer-max (T13): rescale only when row max grows past threshold
            if (!__all(pmax <= m_ + 11.5f)) {
                float mx = fmaxf(pmax, __shfl_xor(pmax, 16));
                mx = fmaxf(mx, __shfl_xor(mx, 32));
                float nm = fmaxf(m_, mx);
                float fs = ex2(m_ - nm);
                m_ = nm;
                ls *= fs;
                float fsr[4];
#pragma unroll
                for (int r = 0; r < 4; ++r) fsr[r] = __shfl(fs, g * 4 + r);
#pragma unroll
                for (int d = 0; d < 4; ++d)
#pragma unroll
                    for (int r = 0; r < 4; ++r) o[d][r] *= fsr[r];
            }
            float rs = 0.f;
#pragma unroll
            for (int ks = 0; ks < 4; ++ks)
#pragma unroll
                for (int r = 0; r < 4; ++r) {
                    p[ks][r] = ex2(p[ks][r] - m_);
                    rs += p[ks][r];
                }
            rs += __shfl_xor(rs, 16);
            rs += __shfl_xor(rs, 32);
            ls += rs;

            // ---- P -> LDS: pack 4 bf16 per ks via cvt_pk, one b64 write ----
#pragma unroll
            for (int ks = 0; ks < 4; ++ks) {
                uint u0, u1;
                asm("v_cvt_pk_bf16_f32 %0, %1, %2" : "=v"(u0) : "v"(p[ks][0]), "v"(p[ks][1]));
                asm("v_cvt_pk_bf16_f32 %0, %1, %2" : "=v"(u1) : "v"(p[ks][2]), "v"(p[ks][3]));
                uint2 uv; uv.x = u0; uv.y = u1;
                *(uint2*)(Pw + li * 128 + ((ks * 32 + g * 8) ^ ((li & 7) << 4))) = uv;
            }

            // ---- PV: P A-frags (row=q=li) + V B-frags from swizzled LDS ----
            s16x8 pf[2];
#pragma unroll
            for (int ks2 = 0; ks2 < 2; ++ks2)
                pf[ks2] = *(const s16x8*)(Pw + li * 128 + ((ks2 * 64 + g * 16) ^ ((li & 7) << 4)));
#pragma unroll
            for (int dblk = 0; dblk < 4; ++dblk) {
                int vrow = dblk * 16 + li;
#pragma unroll
                for (int ks2 = 0; ks2 < 2; ++ks2) {
                    s16x8 vf = *(const s16x8*)(Vs[cur] + vrow * 128 + ((ks2 * 64 + g * 16) ^ rswz));
                    __builtin_amdgcn_s_setprio(1);
                    o[dblk] = __builtin_amdgcn_mfma_f32_16x16x32_bf16(pf[ks2], vf, o[dblk], 0, 0, 0);
                    __builtin_amdgcn_s_setprio(0);
                }
            }
            __syncthreads();   // drains vmcnt (stage done) + protects buffer reuse
        }

        // ---- epilogue: o[dblk][r] holds out[q=qw+g*4+r][d=dblk*16+li] ----
        float lsr[4];
#pragma unroll
        for (int r = 0; r < 4; ++r) lsr[r] = __shfl(ls, g * 4 + r);
#pragma unroll
        for (int r = 0; r < 4; ++r) {
            float inv = 1.0f / lsr[r];
            ushort* cp = ctx + (size_t)(b * SS + qw + g * 4 + r) * D_MODEL + h * DK;
#pragma unroll
            for (int dblk = 0; dblk < 4; ++dblk)
                cp[dblk * 16 + li] = f2bf(o[dblk][r] * inv);
        }
    }
}

// ------------------- residual (+split-K partials) + LayerNorm --------------
// z = xa + xb (+ xc if X3): xb/xc are the two split-K partial outputs.
template <bool WBF, bool X3>
__global__ __launch_bounds__(256) void ln_fused(
        const float* __restrict__ xa, const float* __restrict__ xb,
        const float* __restrict__ xc,
        const float* __restrict__ gamma, const float* __restrict__ beta,
        float* __restrict__ outf, ushort* __restrict__ outb) {
    const int row = blockIdx.x;
    const int t   = threadIdx.x;
    const size_t off = (size_t)row * D_MODEL + t * 4;
    float4 a = *(const float4*)(xa + off);
    float4 c = *(const float4*)(xb + off);
    float z0 = a.x + c.x, z1 = a.y + c.y, z2 = a.z + c.z, z3 = a.w + c.w;
    if constexpr (X3) {
        float4 d = *(const float4*)(xc + off);
        z0 += d.x; z1 += d.y; z2 += d.z; z3 += d.w;
    }
    float sum = z0 + z1 + z2 + z3;
    float sq  = z0 * z0 + z1 * z1 + z2 * z2 + z3 * z3;
#pragma unroll
    for (int o = 1; o < 64; o <<= 1) {
        sum += __shfl_xor(sum, o);
        sq  += __shfl_xor(sq, o);
    }
    __shared__ float s1[4], s2[4];
    if ((t & 63) == 0) { s1[t >> 6] = sum; s2[t >> 6] = sq; }
    __syncthreads();
    float tot = s1[0] + s1[1] + s1[2] + s1[3];
    float tsq = s2[0] + s2[1] + s2[2] + s2[3];
    const float invn = 1.0f / (float)D_MODEL;
    float mu  = tot * invn;
    float var = tsq * invn - mu * mu;
    float rstd = rsqrtf(var + 1e-5f);
    float4 gv = *(const float4*)(gamma + t * 4);
    float4 bv = *(const float4*)(beta + t * 4);
    float y0 = (z0 - mu) * rstd * gv.x + bv.x;
    float y1 = (z1 - mu) * rstd * gv.y + bv.y;
    float y2 = (z2 - mu) * rstd * gv.z + bv.z;
    float y3 = (z3 - mu) * rstd * gv.w + bv.w;
    float4 y = {y0, y1, y2, y3};
    *(float4*)(outf + off) = y;
    if constexpr (WBF) {
        ushort4 u;
        u.x = f2bf(y0); u.y = f2bf(y1); u.z = f2bf(y2); u.w = f2bf(y3);
        *(ushort4*)(outb + off) = u;
    }
}

// ---------------------------------------------------------------------------
extern "C" void kernel_launch(void* const* d_in, const int* in_sizes, int n_in,
                              void* d_out, int out_size, void* d_ws, size_t ws_size,
                              hipStream_t stream) {
    const float* x   = (const float*)d_in[0];
    const float* wq  = (const float*)d_in[2];  const float* bq  = (const float*)d_in[3];
    const float* wk  = (const float*)d_in[4];  const float* bk  = (const float*)d_in[5];
    const float* wv  = (const float*)d_in[6];  const float* bv  = (const float*)d_in[7];
    const float* wo  = (const float*)d_in[8];  const float* bo  = (const float*)d_in[9];
    const float* w1  = (const float*)d_in[10]; const float* b1  = (const float*)d_in[11];
    const float* w2  = (const float*)d_in[12]; const float* b2  = (const float*)d_in[13];
    const float* g1  = (const float*)d_in[14]; const float* be1 = (const float*)d_in[15];
    const float* g2  = (const float*)d_in[16]; const float* be2 = (const float*)d_in[17];
    float* out = (float*)d_out;

    char* ws = (char*)d_ws;
    const size_t MB = 1u << 20;
    ushort* wqkb = (ushort*)(ws + 0 * MB);    // [2048][1024] bf16 (wq then wk)
    ushort* wvb  = (ushort*)(ws + 4 * MB);
    ushort* wob  = (ushort*)(ws + 6 * MB);
    ushort* w1b  = (ushort*)(ws + 8 * MB);
    ushort* w2b  = (ushort*)(ws + 16 * MB);
    ushort* xb   = (ushort*)(ws + 24 * MB);   // dead after Vt GEMM
    ushort* QKb  = (ushort*)(ws + 32 * MB);   // [4096][2048]; dead after attn
    ushort* VtG  = (ushort*)(ws + 48 * MB);   // [1024][4096]; dead after attn
    ushort* ctx  = (ushort*)(ws + 56 * MB);   // dead after O-proj
    float*  p0   = (float*)(ws + 64 * MB);    // split-K partial 0 (16MB)
    float*  p1   = (float*)(ws + 80 * MB);    // split-K partial 1 (16MB)
    float*  h    = (float*)(ws + 96 * MB);
    ushort* hb   = (ushort*)(ws + 112 * MB);
    ushort* ffib = (ushort*)(ws + 24 * MB);   // 32MB, reuses xb+QKb (both dead)
    // peak usage: 120 MB

    CvtArgs ca;
    ca.src[0] = wq; ca.dst[0] = wqkb;
    ca.src[1] = wk; ca.dst[1] = wqkb + D_MODEL * D_MODEL;
    ca.src[2] = wv; ca.dst[2] = wvb;
    ca.src[3] = wo; ca.dst[3] = wob;
    ca.src[4] = w1; ca.dst[4] = w1b;
    ca.src[5] = w2; ca.dst[5] = w2b;
    ca.src[6] = x;  ca.dst[6] = xb;
    cvt_all<<<dim3(16384), dim3(256), 0, stream>>>(ca);

    dim3 blk(256);
    // fused Q,K projection: [4096][2048]; Q columns pre-scaled by QSCALE
    gemm_bt<false, true, false, true><<<dim3(512), blk, 0, stream>>>(
        xb, wqkb, bq, bk, D_MODEL, QKb, NTOK, 2 * D_MODEL, D_MODEL, D_MODEL, 16, 1);
    // V^T = Wv * X^T : [1024][4096], bias per row
    gemm_bt<false, true, true, false><<<dim3(256), blk, 0, stream>>>(
        wvb, xb, bv, bv, 0, VtG, D_MODEL, NTOK, D_MODEL, D_MODEL, 32, 1);

    attn_kernel<<<dim3(SS / 128, 16, BB), dim3(256), 0, stream>>>(QKb, VtG, ctx);

    // O projection, split-K x2 (one launch, 512 blocks): partials p0,p1
    gemm_bt<false, false, false, false><<<dim3(512), blk, 0, stream>>>(
        ctx, wob, bo, bo, D_MODEL, p0, NTOK, D_MODEL, 512, D_MODEL, 8, 2);
    ln_fused<true, true><<<dim3(NTOK), blk, 0, stream>>>(x, p0, p1, g1, be1, h, hb);

    gemm_bt<true, true, false, false><<<dim3(1024), blk, 0, stream>>>(
        hb, w1b, b1, b1, D_FF, ffib, NTOK, D_FF, D_MODEL, D_MODEL, 32, 1);
    // FFN2, split-K x2 (one launch, 512 blocks): partials p0,p1
    gemm_bt<false, false, false, false><<<dim3(512), blk, 0, stream>>>(
        ffib, w2b, b2, b2, D_MODEL, p0, NTOK, D_MODEL, 2048, D_FF, 8, 2);
    ln_fused<false, true><<<dim3(NTOK), blk, 0, stream>>>(h, p0, p1, g2, be2, out, nullptr);
}